// Round 11
// baseline (29738.660 us; speedup 1.0000x reference)
//
#include <hip/hip_runtime.h>
#include <math.h>

// ============================================================================
// KNet RNN — persistent kernel, round 16: top-counter barrier poll (isolated).
//   Base = round-15 (27.08 ms, passing): 7 epochs/step, sc1 coherent loads
//   via single global_load_dwordx4 sc0 sc1, LDS-persistent W2b, 64-bit stores.
//   Change vs R15 (ONLY the barrier): pollers poll the per-epoch TOP arrival
//   counter (==16 <=> all 16 groups complete <=> all 256 WGs arrived) instead
//   of a separate GO line — removes one LLC round trip (GO store) from the
//   per-epoch critical chain. s_sleep(2) -> s_sleep(1) for faster observe.
//   (This was proposed in R1 but confounded with a failed C-fold; isolated
//   retest per methodology.) Release reasoning: top==16 implies every group
//   line reached 16, each increment control-dep-ordered after that leader's
//   own s_waitcnt(0) drain. Per-epoch counter lines avoid ABA.
// ============================================================================

#define NWG 256
#define NTH 1024
#define TT  256
#define NEPOCH 1792            // 7 * 256
#define EP_STRIDE 272          // 16 group lines (16 ints) + 1 top line
#define OFF_GO   (NEPOCH*EP_STRIDE)
#define INT_TOTAL (OFF_GO + 16)

// float-region offsets
#define F_HQ    0         // [2][16][228]
#define F_HS    7296      // [2][16][228]
#define F_HSIG  14592     // [16][228]
#define F_XP    18240     // [240]
#define F_DY    18480     // [16][16]
#define F_FWD   18736     // [16][16]
#define F_OBSD  18992     // [16][16]
#define F_OSIG  19248     // [16][228]
#define F_OUT1  22896     // [16][228]
#define F_OUT3  26544     // [16][228]
#define F_XV    30192     // [16][452]
#define F_OUT2  37424     // [16][228] atomic-accumulated out2
#define F_HID2  52016     // [16][18000]
#define PQ      340016    // 675 x 304
#define PSIG    545216    // 675 x 544
#define PS      912416    // 675 x 608
#define PW1     1322816   // 225 x 228
#define PW3     1374116   // 225 x 456
#define PW4     1476716   // 225 x 456
#define PW5     1579316   // 75 x 16
#define PW6     1580516   // 75 x 16
#define PW7     1581716   // 150 x 32
#define W2AP    1586516   // 18000 x 452

// LDS layout (floats): [0,18000) persistent W2b tile; [18000,27024) scratch
#define LW2B    0
#define S0      18000
#define L_OUT5  (S0)          // 1216 (stages A,B)
#define L_OUT6  (S0+1216)     // 1216 (stage B)
#define L_OUT7  (S0+2432)     // 2432 (stage D)
#define L_OUT2  (S0+4864)     // 3648 (stage G)
#define L_XV    (S0)          // 7232 (stage E; overlaps OUT5/6/7/2 regions)
#define L_SCR   (S0+8512)     // 512: FWD (A/B) or OBSD|DY (D)
#define L_TOTAL 27024

typedef float v4f __attribute__((ext_vector_type(4)));
typedef unsigned long long u64;

// one-transaction coherent 16B load (L0+L2 bypass -> LLC), exec-masked OK
__device__ __forceinline__ void cld4r(v4f& r, const float* p) {
  asm volatile("global_load_dwordx4 %0, %1, off sc0 sc1"
               : "+v"(r) : "v"(p) : "memory");
}
#define CW1(a)       asm volatile("s_waitcnt vmcnt(0)" : "+v"(a) :: "memory")
#define CW2(a,b)     asm volatile("s_waitcnt vmcnt(0)" : "+v"(a), "+v"(b) :: "memory")
#define CW3(a,b,c)   asm volatile("s_waitcnt vmcnt(0)" : "+v"(a), "+v"(b), "+v"(c) :: "memory")
#define CW4(a,b,c,d) asm volatile("s_waitcnt vmcnt(0)" : "+v"(a), "+v"(b), "+v"(c), "+v"(d) :: "memory")

__device__ __forceinline__ float4 v2f(v4f v) { return make_float4(v.x, v.y, v.z, v.w); }

struct KArgs {
  const float *y,*x0,*hQ0,*hSig0,*hS0;
  const float *WihQ,*WhhQ,*bihQ,*bhhQ;
  const float *WihSig,*WhhSig,*bihSig,*bhhSig;
  const float *WihS,*WhhS,*bihS,*bhhS;
  const float *W1,*b1,*W2a,*b2a,*W2b,*b2b,*W3,*b3,*W4,*b4;
  const float *W5,*b5,*W6,*b6,*W7,*b7;
  float* out;
  int*   ib;
  float* fb;
};

__device__ __forceinline__ float sigf(float x) { return 1.0f/(1.0f + __expf(-x)); }
__device__ __forceinline__ float dp4(float acc, float4 w, float4 x) {
  acc = fmaf(w.x, x.x, acc); acc = fmaf(w.y, x.y, acc);
  acc = fmaf(w.z, x.z, acc); acc = fmaf(w.w, x.w, acc);
  return acc;
}
__device__ __forceinline__ float4 ldg4(const float* p){ return *(const float4*)p; }

// coherent (sc-bypass) accessors for cross-WG communicated data
__device__ __forceinline__ float ald(const float* p) {
  return __hip_atomic_load(p, __ATOMIC_RELAXED, __HIP_MEMORY_SCOPE_AGENT);
}
__device__ __forceinline__ void ast(float* p, float v) {
  __hip_atomic_store(p, v, __ATOMIC_RELAXED, __HIP_MEMORY_SCOPE_AGENT);
}
__device__ __forceinline__ void ast2(float* p, float x, float y) {
  u64 u = (u64)__float_as_uint(x) | ((u64)__float_as_uint(y) << 32);
  __hip_atomic_store((u64*)p, u, __ATOMIC_RELAXED, __HIP_MEMORY_SCOPE_AGENT);
}
__device__ __forceinline__ void ast4(float* p, float4 v) {
  ast2(p, v.x, v.y); ast2(p + 2, v.z, v.w);
}
__device__ __forceinline__ void aadd(float* p, float v) {
  __hip_atomic_fetch_add(p, v, __ATOMIC_RELAXED, __HIP_MEMORY_SCOPE_AGENT);
}

__device__ __forceinline__ float red64(float v) {
  v += __shfl_xor(v, 1, 64);  v += __shfl_xor(v, 2, 64);
  v += __shfl_xor(v, 4, 64);  v += __shfl_xor(v, 8, 64);
  v += __shfl_xor(v, 16, 64); v += __shfl_xor(v, 32, 64);
  return v;
}

// Fence-free barrier: every thread drains its own sc-stores (vmcnt 0), then
// thread 0 does relaxed two-level arrival; pollers poll the per-epoch TOP
// counter (==16 iff all 256 WGs arrived; each increment control-dep-ordered
// after that WG's drain).
__device__ __forceinline__ void gbar(int* ib, int e) {
  __builtin_amdgcn_s_waitcnt(0);
  __syncthreads();
  if (threadIdx.x == 0) {
    int* base = ib + e * EP_STRIDE;
    const int g = (int)(blockIdx.x >> 4);
    int prev = __hip_atomic_fetch_add(base + g*16, 1,
                                      __ATOMIC_RELAXED, __HIP_MEMORY_SCOPE_AGENT);
    if (prev == 15)
      __hip_atomic_fetch_add(base + 256, 1,
                             __ATOMIC_RELAXED, __HIP_MEMORY_SCOPE_AGENT);
    while (__hip_atomic_load(base + 256, __ATOMIC_RELAXED, __HIP_MEMORY_SCOPE_AGENT) < 16)
      __builtin_amdgcn_s_sleep(1);
  }
  __syncthreads();
}

__global__ void knet_init(KArgs a) {
  int gt = blockIdx.x*blockDim.x + threadIdx.x;
  int nt = gridDim.x*blockDim.x;
  float* F = a.fb;
  for (int i = gt; i < INT_TOTAL; i += nt) a.ib[i] = 0;
  for (int i = gt; i < 3648; i += nt) {
    int b = i/228, j = i - b*228;
    float hq=0.f, hs=0.f, hg=0.f;
    if (j < 225) { hq = a.hQ0[b*225+j]; hs = a.hS0[b*225+j]; hg = a.hSig0[b*225+j]; }
    F[F_HQ + i] = hq; F[F_HS + i] = hs; F[F_HSIG + i] = hg;
    F[F_OSIG + i] = 0.f; F[F_OUT3 + i] = 0.f; F[F_OUT1 + i] = 0.f;
    F[F_OUT2 + i] = 0.f;
  }
  for (int i = gt; i < 7232; i += nt) F[F_XV + i] = 0.f;
  for (int i = gt; i < 240; i += nt) F[F_XP + i] = a.x0[i];
  for (int i = gt; i < 256; i += nt) {
    int b = i >> 4, j = i & 15;
    float dy=0.f, od=0.f;
    if (j < 15) {
      float ob = a.y[b*30 + j], xv = a.x0[b*15 + j];
      dy = ob - xv; od = ob - xv;
    }
    F[F_DY + i] = dy; F[F_OBSD + i] = od; F[F_FWD + i] = 0.f;
  }
  for (int i = gt; i < 675*304; i += nt) {
    int r = i/304, d = i - r*304; float v = 0.f;
    if (d < 75) v = a.WihQ[r*75 + d];
    else if (d >= 76 && d < 301) v = a.WhhQ[r*225 + d - 76];
    F[PQ + i] = v;
  }
  for (int i = gt; i < 675*544; i += nt) {
    int r = i/544, d = i - r*544; float v = 0.f;
    if (d < 225) v = a.WihSig[r*300 + d];
    else if (d >= 228 && d < 303) v = a.WihSig[r*300 + 225 + d - 228];
    else if (d >= 304 && d < 529) v = a.WhhSig[r*225 + d - 304];
    F[PSIG + i] = v;
  }
  for (int i = gt; i < 675*608; i += nt) {
    int r = i/608, d = i - r*608; float v = 0.f;
    if (d < 225) v = a.WihS[r*375 + d];
    else if (d >= 228 && d < 378) v = a.WihS[r*375 + 225 + d - 228];
    else if (d >= 380 && d < 605) v = a.WhhS[r*225 + d - 380];
    F[PS + i] = v;
  }
  for (int i = gt; i < 225*228; i += nt) {
    int r = i/228, d = i - r*228;
    F[PW1 + i] = (d < 225) ? a.W1[r*225 + d] : 0.f;
  }
  for (int i = gt; i < 225*456; i += nt) {
    int r = i/456, d = i - r*456; float v3 = 0.f, v4 = 0.f;
    if (d < 225)               { v3 = a.W3[r*450 + d];           v4 = a.W4[r*450 + d]; }
    else if (d >= 228 && d < 453) { v3 = a.W3[r*450 + 225 + d - 228]; v4 = a.W4[r*450 + 225 + d - 228]; }
    F[PW3 + i] = v3; F[PW4 + i] = v4;
  }
  for (int i = gt; i < 75*16; i += nt) {
    int r = i >> 4, d = i & 15;
    F[PW5 + i] = (d < 15) ? a.W5[r*15 + d] : 0.f;
    F[PW6 + i] = (d < 15) ? a.W6[r*15 + d] : 0.f;
  }
  for (int i = gt; i < 150*32; i += nt) {
    int r = i >> 5, d = i & 31; float v = 0.f;
    if (d < 15) v = a.W7[r*30 + d];
    else if (d >= 16 && d < 31) v = a.W7[r*30 + 15 + d - 16];
    F[PW7 + i] = v;
  }
  for (long long i = gt; i < 18000LL*452; i += nt) {
    long long r = i/452; int d = (int)(i - r*452);
    F[W2AP + i] = (d < 450) ? a.W2a[r*450 + d] : 0.f;
  }
}

__global__ __launch_bounds__(NTH, 4) void knet_main(KArgs a) {
  __shared__ float smem[L_TOTAL];
  const int tid  = threadIdx.x;
  const int widx = tid >> 6;
  const int l    = tid & 63;
  const int bx   = (int)blockIdx.x;
  const int k0   = l*4;
  float* F  = a.fb;
  int*   ib = a.ib;
  int ep = 0;

  // One-time: preload this WG's constant W2b tile [45][400] into LDS.
  if (bx < 225) {
    const int jt = bx / 45, kc = bx - jt*45;
    const int j0 = jt*45, col0 = kc*400;
    for (int idx = tid; idx < 4500; idx += NTH) {
      int jj = idx / 100, cc = idx - jj*100;
      *(float4*)(smem + LW2B + jj*400 + cc*4) =
          ldg4(a.W2b + (size_t)(j0+jj)*18000 + col0 + cc*4);
    }
  }
  __syncthreads();

  for (int t = 0; t < TT; ++t) {
    const int p = t & 1, q = p ^ 1;
    float* hQi = F + F_HQ + p*3648;  float* hQo = F + F_HQ + q*3648;
    float* hSi = F + F_HS + p*3648;  float* hSo = F + F_HS + q*3648;

    // ==== A: out5(LDS) ; hQ GRU ; hSig = out4(prev osig,out3) ==============
    if (bx < 225) {
      if (tid < 64) {
        v4f v = {0.f,0.f,0.f,0.f};
        cld4r(v, F + F_FWD + tid*4);
        CW1(v);
        *(float4*)(smem + L_SCR + tid*4) = v2f(v);
      }
      __syncthreads();
      for (int i = tid; i < 1200; i += NTH) {
        int bb = i/75, j5 = i - bb*75;
        const float4* w  = (const float4*)(F + PW5 + j5*16);
        const float4* xv = (const float4*)(smem + L_SCR + bb*16);
        float acc = a.b5[j5];
        acc = dp4(acc, w[0], xv[0]); acc = dp4(acc, w[1], xv[1]);
        acc = dp4(acc, w[2], xv[2]); acc = dp4(acc, w[3], xv[3]);
        smem[L_OUT5 + bb*76 + j5] = fmaxf(acc, 0.f);
      }
      __syncthreads();
      const int j = bx, bw = widx;
      v4f tq0 = {0.f,0.f,0.f,0.f}, tq1 = {0.f,0.f,0.f,0.f};
      v4f tw0 = {0.f,0.f,0.f,0.f}, tw1 = {0.f,0.f,0.f,0.f};
      if (k0 >= 76) cld4r(tq0, hQi + bw*228 + k0 - 76);
      if (l < 12)   cld4r(tq1, hQi + bw*228 + 180 + k0);
      cld4r(tw0, (l < 57) ? (F + F_OSIG + bw*228 + k0)
                          : (F + F_OUT3 + bw*228 + k0 - 228));
      if (l < 50)   cld4r(tw1, F + F_OUT3 + bw*228 + 28 + k0);
      CW4(tq0, tq1, tw0, tw1);
      float4 xq0 = (k0 < 76) ? *(const float4*)(smem + L_OUT5 + bw*76 + k0)
                             : v2f(tq0);
      float4 xq1 = v2f(tq1);
      float4 xw0 = v2f(tw0);
      float4 xw1 = v2f(tw1);
      const float* qr = F + PQ + (size_t)j*304;
      const float* qz = qr + 225*304;
      const float* qn = qr + 450*304;
      const float* w4r = F + PW4 + (size_t)j*456;
      float4 wr0 = ldg4(qr + k0), wz0 = ldg4(qz + k0), wn0 = ldg4(qn + k0);
      float4 w40 = ldg4(w4r + k0);
      float ar=0.f, az=0.f, ani=0.f, anh=0.f, a4=0.f;
      ar = dp4(ar, wr0, xq0); az = dp4(az, wz0, xq0);
      { float tt = dp4(0.f, wn0, xq0); if (k0 < 76) ani += tt; else anh += tt; }
      a4 = dp4(a4, w40, xw0);
      if (l < 12) {
        float4 wr1 = ldg4(qr + 256 + k0), wz1 = ldg4(qz + 256 + k0), wn1 = ldg4(qn + 256 + k0);
        ar = dp4(ar, wr1, xq1); az = dp4(az, wz1, xq1); anh = dp4(anh, wn1, xq1);
      }
      if (l < 50) a4 = dp4(a4, ldg4(w4r + 256 + k0), xw1);
      ar = red64(ar); az = red64(az); ani = red64(ani); anh = red64(anh); a4 = red64(a4);
      if (l == 0) {
        float r = sigf(ar + a.bihQ[j] + a.bhhQ[j]);
        float z = sigf(az + a.bihQ[225+j] + a.bhhQ[225+j]);
        float n = tanhf(ani + a.bihQ[450+j] + r*(anh + a.bhhQ[450+j]));
        ast(&hQo[bw*228 + j], (1.f - z)*n + z*ald(&hQi[bw*228 + j]));
        if (t > 0) ast(&F[F_HSIG + bw*228 + j], fmaxf(a4 + a.b4[j], 0.f));
      }
    } else if (bx == 225) {
      // zero out2 for this step's F-stage atomic accumulation
      for (int i = tid; i < 912; i += NTH)
        ast4(&F[F_OUT2 + i*4], make_float4(0.f, 0.f, 0.f, 0.f));
    }
    gbar(ib, ep); ++ep;

    // ==== B: out6(LDS) ; osig GRU (x=[hQ|out6], h=hSig) ====================
    if (bx < 225) {
      // FWD still in L_SCR from stage A
      for (int i = tid; i < 1200; i += NTH) {
        int bb = i/75, j6 = i - bb*75;
        const float4* w  = (const float4*)(F + PW6 + j6*16);
        const float4* xv = (const float4*)(smem + L_SCR + bb*16);
        float acc = a.b6[j6];
        acc = dp4(acc, w[0], xv[0]); acc = dp4(acc, w[1], xv[1]);
        acc = dp4(acc, w[2], xv[2]); acc = dp4(acc, w[3], xv[3]);
        smem[L_OUT6 + bb*76 + j6] = fmaxf(acc, 0.f);
      }
      __syncthreads();
      const int j = bx, bw = widx;
      v4f t0 = {0.f,0.f,0.f,0.f}, t1 = {0.f,0.f,0.f,0.f}, t2 = {0.f,0.f,0.f,0.f};
      if (l < 57)  cld4r(t0, hQo + bw*228 + k0);
      if (l >= 12) cld4r(t1, F + F_HSIG + bw*228 + k0 - 48);
      if (l < 5)   cld4r(t2, F + F_HSIG + bw*228 + 208 + k0);
      CW3(t0, t1, t2);
      float4 x0 = (l < 57) ? v2f(t0)
                           : *(const float4*)(smem + L_OUT6 + bw*76 + k0 - 228);
      float4 x1 = (l < 12) ? *(const float4*)(smem + L_OUT6 + bw*76 + 28 + k0)
                           : v2f(t1);
      float4 x2 = v2f(t2);
      const float* gr = F + PSIG + (size_t)j*544;
      const float* gz = gr + 225*544;
      const float* gn = gr + 450*544;
      float4 wr0 = ldg4(gr + k0),     wz0 = ldg4(gz + k0),     wn0 = ldg4(gn + k0);
      float4 wr1 = ldg4(gr + 256+k0), wz1 = ldg4(gz + 256+k0), wn1 = ldg4(gn + 256+k0);
      float ar=0.f, az=0.f, ani=0.f, anh=0.f;
      ar = dp4(ar, wr0, x0); az = dp4(az, wz0, x0); ani = dp4(ani, wn0, x0);
      ar = dp4(ar, wr1, x1); az = dp4(az, wz1, x1);
      { float tt = dp4(0.f, wn1, x1); if (l < 12) ani += tt; else anh += tt; }
      if (l < 5) {
        float4 wr2 = ldg4(gr + 512+k0), wz2 = ldg4(gz + 512+k0), wn2 = ldg4(gn + 512+k0);
        ar = dp4(ar, wr2, x2); az = dp4(az, wz2, x2); anh = dp4(anh, wn2, x2);
      }
      ar = red64(ar); az = red64(az); ani = red64(ani); anh = red64(anh);
      if (l == 0) {
        float r = sigf(ar + a.bihSig[j] + a.bhhSig[j]);
        float z = sigf(az + a.bihSig[225+j] + a.bhhSig[225+j]);
        float n = tanhf(ani + a.bihSig[450+j] + r*(anh + a.bhhSig[450+j]));
        float val = (1.f - z)*n + z*ald(&F[F_HSIG + bw*228 + j]);
        ast(&F[F_OSIG + bw*228 + j], val);
        ast(&F[F_XV + bw*452 + j], val);
      }
    }
    gbar(ib, ep); ++ep;

    // ==== C: out1 = relu(W1 @ osig + b1) ===================================
    if (bx < 225) {
      const int j = bx, bw = widx;
      float acc = 0.f;
      v4f t0 = {0.f,0.f,0.f,0.f};
      if (l < 57) cld4r(t0, F + F_OSIG + bw*228 + k0);
      CW1(t0);
      if (l < 57) {
        float4 w0 = ldg4(F + PW1 + (size_t)j*228 + k0);
        acc = dp4(0.f, w0, v2f(t0));
      }
      acc = red64(acc);
      if (l == 0) ast(&F[F_OUT1 + bw*228 + j], fmaxf(acc + a.b1[j], 0.f));
    }
    gbar(ib, ep); ++ep;

    // ==== D: out7(LDS) ; hS GRU (x=[out1|out7], h=hS) ======================
    if (bx < 225) {
      if (tid < 128) {
        v4f v = {0.f,0.f,0.f,0.f};
        cld4r(v, (tid < 64) ? (F + F_OBSD + tid*4) : (F + F_DY + (tid-64)*4));
        CW1(v);
        *(float4*)(smem + L_SCR + tid*4) = v2f(v);
      }
      __syncthreads();
      for (int i = tid; i < 2400; i += NTH) {
        int bb = i/150, j7 = i - bb*150;
        const float4* w  = (const float4*)(F + PW7 + j7*32);
        const float4* vo = (const float4*)(smem + L_SCR + bb*16);
        const float4* vd = (const float4*)(smem + L_SCR + 256 + bb*16);
        float acc = a.b7[j7];
        acc = dp4(acc, w[0], vo[0]); acc = dp4(acc, w[1], vo[1]);
        acc = dp4(acc, w[2], vo[2]); acc = dp4(acc, w[3], vo[3]);
        acc = dp4(acc, w[4], vd[0]); acc = dp4(acc, w[5], vd[1]);
        acc = dp4(acc, w[6], vd[2]); acc = dp4(acc, w[7], vd[3]);
        smem[L_OUT7 + bb*152 + j7] = fmaxf(acc, 0.f);
      }
      __syncthreads();
      const int j = bx, bw = widx;
      v4f t0 = {0.f,0.f,0.f,0.f}, t1 = {0.f,0.f,0.f,0.f}, t2 = {0.f,0.f,0.f,0.f};
      if (l < 57)  cld4r(t0, F + F_OUT1 + bw*228 + k0);
      if (l >= 31) cld4r(t1, hSi + bw*228 + k0 - 124);
      if (l < 24)  cld4r(t2, hSi + bw*228 + 132 + k0);
      CW3(t0, t1, t2);
      float4 x0 = (l < 57) ? v2f(t0)
                           : *(const float4*)(smem + L_OUT7 + bw*152 + k0 - 228);
      float4 x1 = (l < 31) ? *(const float4*)(smem + L_OUT7 + bw*152 + 28 + k0)
                           : v2f(t1);
      float4 x2 = v2f(t2);
      const float* gr = F + PS + (size_t)j*608;
      const float* gz = gr + 225*608;
      const float* gn = gr + 450*608;
      float4 wr0 = ldg4(gr + k0),     wz0 = ldg4(gz + k0),     wn0 = ldg4(gn + k0);
      float4 wr1 = ldg4(gr + 256+k0), wz1 = ldg4(gz + 256+k0), wn1 = ldg4(gn + 256+k0);
      float ar=0.f, az=0.f, ani=0.f, anh=0.f;
      ar = dp4(ar, wr0, x0); az = dp4(az, wz0, x0); ani = dp4(ani, wn0, x0);
      ar = dp4(ar, wr1, x1); az = dp4(az, wz1, x1);
      { float tt = dp4(0.f, wn1, x1); if (l < 31) ani += tt; else anh += tt; }
      if (l < 24) {
        float4 wr2 = ldg4(gr + 512+k0), wz2 = ldg4(gz + 512+k0), wn2 = ldg4(gn + 512+k0);
        ar = dp4(ar, wr2, x2); az = dp4(az, wz2, x2); anh = dp4(anh, wn2, x2);
      }
      ar = red64(ar); az = red64(az); ani = red64(ani); anh = red64(anh);
      if (l == 0) {
        float r = sigf(ar + a.bihS[j] + a.bhhS[j]);
        float z = sigf(az + a.bihS[225+j] + a.bhhS[225+j]);
        float n = tanhf(ani + a.bihS[450+j] + r*(anh + a.bhhS[450+j]));
        float val = (1.f - z)*n + z*ald(&hSi[bw*228 + j]);
        ast(&hSo[bw*228 + j], val);
        ast(&F[F_XV + bw*452 + 225 + j], val);
      }
    }
    gbar(ib, ep); ++ep;

    // ==== E: hid2 = relu(W2aP @ xv + b2a) — 2 rows x 16 b per wave =========
    {
      {
        const int i0 = tid, i1 = tid + NTH;
        v4f v0 = {0.f,0.f,0.f,0.f}, v1 = {0.f,0.f,0.f,0.f};
        cld4r(v0, F + F_XV + i0*4);
        if (i1 < 1808) cld4r(v1, F + F_XV + i1*4);
        CW2(v0, v1);
        *(float4*)(smem + L_XV + i0*4) = v2f(v0);
        if (i1 < 1808) *(float4*)(smem + L_XV + i1*4) = v2f(v1);
      }
      __syncthreads();
      if (bx < 250) {
        const int r0 = bx*72;
        for (int ps = 0; ps < 3; ++ps) {
          const int pi = ps*16 + widx;
          if (pi >= 36) break;
          const int rA = r0 + 2*pi;
          const float* wAp = F + W2AP + (size_t)rA*452;
          const float* wBp = wAp + 452;
          float aA[16], aB[16];
          #pragma unroll
          for (int i = 0; i < 16; ++i) { aA[i] = 0.f; aB[i] = 0.f; }
          {
            float4 wA = ldg4(wAp + k0), wB = ldg4(wBp + k0);
            #pragma unroll
            for (int bb = 0; bb < 16; ++bb) {
              float4 xv = *(const float4*)(smem + L_XV + bb*452 + k0);
              aA[bb] = dp4(aA[bb], wA, xv);
              aB[bb] = dp4(aB[bb], wB, xv);
            }
          }
          if (l < 49) {
            float4 wA = ldg4(wAp + 256 + k0), wB = ldg4(wBp + 256 + k0);
            #pragma unroll
            for (int bb = 0; bb < 16; ++bb) {
              float4 xv = *(const float4*)(smem + L_XV + bb*452 + 256 + k0);
              aA[bb] = dp4(aA[bb], wA, xv);
              aB[bb] = dp4(aB[bb], wB, xv);
            }
          }
          #pragma unroll
          for (int i = 0; i < 16; ++i) { aA[i] = red64(aA[i]); aB[i] = red64(aB[i]); }
          if (l == 0) {
            float bA = a.b2a[rA], bB = a.b2a[rA + 1];
            #pragma unroll
            for (int i = 0; i < 16; ++i)
              ast2(&F[F_HID2 + i*18000 + rA],
                   fmaxf(aA[i] + bA, 0.f), fmaxf(aB[i] + bB, 0.f));
          }
        }
      }
    }
    gbar(ib, ep); ++ep;

    // ==== F: out2 += W2b(LDS) @ hid2-chunk — 225 WGs: jt=bx/45, kc=bx%45 ===
    // W2b tile persistent in LDS; no staging, no internal barriers.
    if (bx < 225) {
      const int jt = bx / 45, kc = bx - jt*45;
      const int j0 = jt*45, col0 = kc*400;
      const int b = widx;
      const float* hb = F + F_HID2 + (size_t)b*18000 + col0;
      v4f h0v = {0.f,0.f,0.f,0.f}, h1v = {0.f,0.f,0.f,0.f};
      cld4r(h0v, hb + 4*l);
      if (l < 36) cld4r(h1v, hb + 256 + 4*l);
      CW2(h0v, h1v);
      float4 h0 = v2f(h0v), h1 = v2f(h1v);
      #pragma unroll 5
      for (int jj = 0; jj < 45; ++jj) {
        const float* wrow = smem + LW2B + jj*400;
        float acc = dp4(0.f, *(const float4*)(wrow + 4*l), h0);
        if (l < 36) acc = dp4(acc, *(const float4*)(wrow + 256 + 4*l), h1);
        acc = red64(acc);
        if (l == 0) aadd(&F[F_OUT2 + b*228 + j0 + jj], acc);
      }
    }
    gbar(ib, ep); ++ep;

    // ==== G: out2(LDS) ; out3 = relu(W3@[hS|out2]+b3) ; x update ===========
    if (bx < 225) {
      if (tid < 912) {
        v4f pq = {0.f,0.f,0.f,0.f};
        cld4r(pq, F + F_OUT2 + tid*4);
        CW1(pq);
        int bb = tid / 57, c = tid - bb*57;
        int j2 = c*4;
        float4 v;
        v.x = (j2+0 < 225) ? pq.x + a.b2b[j2+0] : 0.f;
        v.y = (j2+1 < 225) ? pq.y + a.b2b[j2+1] : 0.f;
        v.z = (j2+2 < 225) ? pq.z + a.b2b[j2+2] : 0.f;
        v.w = (j2+3 < 225) ? pq.w + a.b2b[j2+3] : 0.f;
        *(float4*)(smem + L_OUT2 + tid*4) = v;
      }
      __syncthreads();
      const int j = bx, bw = widx;
      v4f t0 = {0.f,0.f,0.f,0.f};
      if (l < 57) cld4r(t0, hSo + bw*228 + k0);
      CW1(t0);
      float4 x0 = (l < 57) ? v2f(t0)
                           : *(const float4*)(smem + L_OUT2 + bw*228 + k0 - 228);
      float4 x1; if (l < 50) x1 = *(const float4*)(smem + L_OUT2 + bw*228 + 28 + k0);
      const float* w3r = F + PW3 + (size_t)j*456;
      float acc = dp4(0.f, ldg4(w3r + k0), x0);
      if (l < 50) acc = dp4(acc, ldg4(w3r + 256 + k0), x1);
      acc = red64(acc);
      if (l == 0) ast(&F[F_OUT3 + bw*228 + j], fmaxf(acc + a.b3[j], 0.f));
    } else if (bx == 225) {
      for (int i = tid; i < 240; i += NTH) {
        int bb = i/15, jj = i - bb*15;
        float o2 = ald(&F[F_OUT2 + bb*228 + jj]) + a.b2b[jj];
        float xold = ald(&F[F_XP + i]), dy = ald(&F[F_DY + bb*16 + jj]);
        float xnew = fmaf(o2, dy, xold);
        a.out[t*240 + i] = xnew;
        ast(&F[F_XP + i], xnew);
        if (t + 1 < TT) {
          float y1 = a.y[(t+1)*480 + bb*30 + jj];
          float y0 = a.y[t*480     + bb*30 + jj];
          ast(&F[F_DY   + bb*16 + jj], y1 - xnew);
          ast(&F[F_OBSD + bb*16 + jj], y1 - y0);
          ast(&F[F_FWD  + bb*16 + jj], xnew - xold);
        }
      }
    }
    gbar(ib, ep); ++ep;
  }
}

extern "C" void kernel_launch(void* const* d_in, const int* in_sizes, int n_in,
                              void* d_out, int out_size, void* d_ws, size_t ws_size,
                              hipStream_t stream) {
  (void)in_sizes; (void)n_in; (void)out_size; (void)ws_size;
  KArgs a;
  int k = 0;
  a.y      = (const float*)d_in[k++];
  a.x0     = (const float*)d_in[k++];
  a.hQ0    = (const float*)d_in[k++];
  a.hSig0  = (const float*)d_in[k++];
  a.hS0    = (const float*)d_in[k++];
  a.WihQ   = (const float*)d_in[k++];
  a.WhhQ   = (const float*)d_in[k++];
  a.bihQ   = (const float*)d_in[k++];
  a.bhhQ   = (const float*)d_in[k++];
  a.WihSig = (const float*)d_in[k++];
  a.WhhSig = (const float*)d_in[k++];
  a.bihSig = (const float*)d_in[k++];
  a.bhhSig = (const float*)d_in[k++];
  a.WihS   = (const float*)d_in[k++];
  a.WhhS   = (const float*)d_in[k++];
  a.bihS   = (const float*)d_in[k++];
  a.bhhS   = (const float*)d_in[k++];
  a.W1  = (const float*)d_in[k++];  a.b1  = (const float*)d_in[k++];
  a.W2a = (const float*)d_in[k++];  a.b2a = (const float*)d_in[k++];
  a.W2b = (const float*)d_in[k++];  a.b2b = (const float*)d_in[k++];
  a.W3  = (const float*)d_in[k++];  a.b3  = (const float*)d_in[k++];
  a.W4  = (const float*)d_in[k++];  a.b4  = (const float*)d_in[k++];
  a.W5  = (const float*)d_in[k++];  a.b5  = (const float*)d_in[k++];
  a.W6  = (const float*)d_in[k++];  a.b6  = (const float*)d_in[k++];
  a.W7  = (const float*)d_in[k++];  a.b7  = (const float*)d_in[k++];
  a.out = (float*)d_out;
  a.ib  = (int*)d_ws;
  a.fb  = (float*)((char*)d_ws + (size_t)INT_TOTAL*sizeof(int));

  hipLaunchKernelGGL(knet_init, dim3(2048), dim3(256), 0, stream, a);
  hipLaunchKernelGGL(knet_main, dim3(NWG), dim3(NTH), 0, stream, a);
}

// Round 13
// 27041.245 us; speedup vs baseline: 1.0998x; 1.0998x over previous
//
#include <hip/hip_runtime.h>
#include <math.h>

// ============================================================================
// KNet RNN — persistent kernel, round 17b: R15 best-state (resubmit after
//   infra failure — container died, not the kernel; this exact code measured
//   27.08 ms passing in round 10).
//   7 epochs/step; sc1 coherent 16B loads via global_load_dwordx4 sc0 sc1
//   (one LLC transaction per float4, data-tied vmcnt waits); 64-bit sc1
//   stores; LDS-persistent W2b tile in stage F; atomicAdd out2; GO-line
//   barrier (contention isolator: written once/epoch, polled read-only).
// ============================================================================

#define NWG 256
#define NTH 1024
#define TT  256
#define NEPOCH 1792            // 7 * 256
#define EP_STRIDE 272          // 16 group lines (16 ints) + 1 top line
#define OFF_GO   (NEPOCH*EP_STRIDE)
#define INT_TOTAL (OFF_GO + 16)

// float-region offsets
#define F_HQ    0         // [2][16][228]
#define F_HS    7296      // [2][16][228]
#define F_HSIG  14592     // [16][228]
#define F_XP    18240     // [240]
#define F_DY    18480     // [16][16]
#define F_FWD   18736     // [16][16]
#define F_OBSD  18992     // [16][16]
#define F_OSIG  19248     // [16][228]
#define F_OUT1  22896     // [16][228]
#define F_OUT3  26544     // [16][228]
#define F_XV    30192     // [16][452]
#define F_OUT2  37424     // [16][228] atomic-accumulated out2
#define F_HID2  52016     // [16][18000]
#define PQ      340016    // 675 x 304
#define PSIG    545216    // 675 x 544
#define PS      912416    // 675 x 608
#define PW1     1322816   // 225 x 228
#define PW3     1374116   // 225 x 456
#define PW4     1476716   // 225 x 456
#define PW5     1579316   // 75 x 16
#define PW6     1580516   // 75 x 16
#define PW7     1581716   // 150 x 32
#define W2AP    1586516   // 18000 x 452

// LDS layout (floats): [0,18000) persistent W2b tile; [18000,27024) scratch
#define LW2B    0
#define S0      18000
#define L_OUT5  (S0)          // 1216 (stages A,B)
#define L_OUT6  (S0+1216)     // 1216 (stage B)
#define L_OUT7  (S0+2432)     // 2432 (stage D)
#define L_OUT2  (S0+4864)     // 3648 (stage G)
#define L_XV    (S0)          // 7232 (stage E; overlaps OUT5/6/7/2 regions)
#define L_SCR   (S0+8512)     // 512: FWD (A/B) or OBSD|DY (D)
#define L_TOTAL 27024

typedef float v4f __attribute__((ext_vector_type(4)));
typedef unsigned long long u64;

// one-transaction coherent 16B load (L0+L2 bypass -> LLC), exec-masked OK
__device__ __forceinline__ void cld4r(v4f& r, const float* p) {
  asm volatile("global_load_dwordx4 %0, %1, off sc0 sc1"
               : "+v"(r) : "v"(p) : "memory");
}
#define CW1(a)       asm volatile("s_waitcnt vmcnt(0)" : "+v"(a) :: "memory")
#define CW2(a,b)     asm volatile("s_waitcnt vmcnt(0)" : "+v"(a), "+v"(b) :: "memory")
#define CW3(a,b,c)   asm volatile("s_waitcnt vmcnt(0)" : "+v"(a), "+v"(b), "+v"(c) :: "memory")
#define CW4(a,b,c,d) asm volatile("s_waitcnt vmcnt(0)" : "+v"(a), "+v"(b), "+v"(c), "+v"(d) :: "memory")

__device__ __forceinline__ float4 v2f(v4f v) { return make_float4(v.x, v.y, v.z, v.w); }

struct KArgs {
  const float *y,*x0,*hQ0,*hSig0,*hS0;
  const float *WihQ,*WhhQ,*bihQ,*bhhQ;
  const float *WihSig,*WhhSig,*bihSig,*bhhSig;
  const float *WihS,*WhhS,*bihS,*bhhS;
  const float *W1,*b1,*W2a,*b2a,*W2b,*b2b,*W3,*b3,*W4,*b4;
  const float *W5,*b5,*W6,*b6,*W7,*b7;
  float* out;
  int*   ib;
  float* fb;
};

__device__ __forceinline__ float sigf(float x) { return 1.0f/(1.0f + __expf(-x)); }
__device__ __forceinline__ float dp4(float acc, float4 w, float4 x) {
  acc = fmaf(w.x, x.x, acc); acc = fmaf(w.y, x.y, acc);
  acc = fmaf(w.z, x.z, acc); acc = fmaf(w.w, x.w, acc);
  return acc;
}
__device__ __forceinline__ float4 ldg4(const float* p){ return *(const float4*)p; }

// coherent (sc-bypass) accessors for cross-WG communicated data
__device__ __forceinline__ float ald(const float* p) {
  return __hip_atomic_load(p, __ATOMIC_RELAXED, __HIP_MEMORY_SCOPE_AGENT);
}
__device__ __forceinline__ void ast(float* p, float v) {
  __hip_atomic_store(p, v, __ATOMIC_RELAXED, __HIP_MEMORY_SCOPE_AGENT);
}
__device__ __forceinline__ void ast2(float* p, float x, float y) {
  u64 u = (u64)__float_as_uint(x) | ((u64)__float_as_uint(y) << 32);
  __hip_atomic_store((u64*)p, u, __ATOMIC_RELAXED, __HIP_MEMORY_SCOPE_AGENT);
}
__device__ __forceinline__ void ast4(float* p, float4 v) {
  ast2(p, v.x, v.y); ast2(p + 2, v.z, v.w);
}
__device__ __forceinline__ void aadd(float* p, float v) {
  __hip_atomic_fetch_add(p, v, __ATOMIC_RELAXED, __HIP_MEMORY_SCOPE_AGENT);
}

__device__ __forceinline__ float red64(float v) {
  v += __shfl_xor(v, 1, 64);  v += __shfl_xor(v, 2, 64);
  v += __shfl_xor(v, 4, 64);  v += __shfl_xor(v, 8, 64);
  v += __shfl_xor(v, 16, 64); v += __shfl_xor(v, 32, 64);
  return v;
}

// Fence-free barrier: every thread drains its own sc-stores (vmcnt 0), then
// thread 0 does relaxed arrival; control deps order group->top->GO.
// GO line is a contention isolator: written once/epoch, polled read-only.
__device__ __forceinline__ void gbar(int* ib, int e) {
  __builtin_amdgcn_s_waitcnt(0);
  __syncthreads();
  if (threadIdx.x == 0) {
    const int base = e * EP_STRIDE;
    const int g = (int)(blockIdx.x >> 4);
    int prev = __hip_atomic_fetch_add(ib + base + g*16, 1,
                                      __ATOMIC_RELAXED, __HIP_MEMORY_SCOPE_AGENT);
    if (prev == 15) {
      int pt = __hip_atomic_fetch_add(ib + base + 256, 1,
                                      __ATOMIC_RELAXED, __HIP_MEMORY_SCOPE_AGENT);
      if (pt == 15)
        __hip_atomic_store(ib + OFF_GO, e, __ATOMIC_RELAXED, __HIP_MEMORY_SCOPE_AGENT);
    }
    while (__hip_atomic_load(ib + OFF_GO, __ATOMIC_RELAXED, __HIP_MEMORY_SCOPE_AGENT) < e)
      __builtin_amdgcn_s_sleep(2);
  }
  __syncthreads();
}

__global__ void knet_init(KArgs a) {
  int gt = blockIdx.x*blockDim.x + threadIdx.x;
  int nt = gridDim.x*blockDim.x;
  float* F = a.fb;
  for (int i = gt; i < INT_TOTAL; i += nt) a.ib[i] = (i == OFF_GO) ? -1 : 0;
  for (int i = gt; i < 3648; i += nt) {
    int b = i/228, j = i - b*228;
    float hq=0.f, hs=0.f, hg=0.f;
    if (j < 225) { hq = a.hQ0[b*225+j]; hs = a.hS0[b*225+j]; hg = a.hSig0[b*225+j]; }
    F[F_HQ + i] = hq; F[F_HS + i] = hs; F[F_HSIG + i] = hg;
    F[F_OSIG + i] = 0.f; F[F_OUT3 + i] = 0.f; F[F_OUT1 + i] = 0.f;
    F[F_OUT2 + i] = 0.f;
  }
  for (int i = gt; i < 7232; i += nt) F[F_XV + i] = 0.f;
  for (int i = gt; i < 240; i += nt) F[F_XP + i] = a.x0[i];
  for (int i = gt; i < 256; i += nt) {
    int b = i >> 4, j = i & 15;
    float dy=0.f, od=0.f;
    if (j < 15) {
      float ob = a.y[b*30 + j], xv = a.x0[b*15 + j];
      dy = ob - xv; od = ob - xv;
    }
    F[F_DY + i] = dy; F[F_OBSD + i] = od; F[F_FWD + i] = 0.f;
  }
  for (int i = gt; i < 675*304; i += nt) {
    int r = i/304, d = i - r*304; float v = 0.f;
    if (d < 75) v = a.WihQ[r*75 + d];
    else if (d >= 76 && d < 301) v = a.WhhQ[r*225 + d - 76];
    F[PQ + i] = v;
  }
  for (int i = gt; i < 675*544; i += nt) {
    int r = i/544, d = i - r*544; float v = 0.f;
    if (d < 225) v = a.WihSig[r*300 + d];
    else if (d >= 228 && d < 303) v = a.WihSig[r*300 + 225 + d - 228];
    else if (d >= 304 && d < 529) v = a.WhhSig[r*225 + d - 304];
    F[PSIG + i] = v;
  }
  for (int i = gt; i < 675*608; i += nt) {
    int r = i/608, d = i - r*608; float v = 0.f;
    if (d < 225) v = a.WihS[r*375 + d];
    else if (d >= 228 && d < 378) v = a.WihS[r*375 + 225 + d - 228];
    else if (d >= 380 && d < 605) v = a.WhhS[r*225 + d - 380];
    F[PS + i] = v;
  }
  for (int i = gt; i < 225*228; i += nt) {
    int r = i/228, d = i - r*228;
    F[PW1 + i] = (d < 225) ? a.W1[r*225 + d] : 0.f;
  }
  for (int i = gt; i < 225*456; i += nt) {
    int r = i/456, d = i - r*456; float v3 = 0.f, v4 = 0.f;
    if (d < 225)               { v3 = a.W3[r*450 + d];           v4 = a.W4[r*450 + d]; }
    else if (d >= 228 && d < 453) { v3 = a.W3[r*450 + 225 + d - 228]; v4 = a.W4[r*450 + 225 + d - 228]; }
    F[PW3 + i] = v3; F[PW4 + i] = v4;
  }
  for (int i = gt; i < 75*16; i += nt) {
    int r = i >> 4, d = i & 15;
    F[PW5 + i] = (d < 15) ? a.W5[r*15 + d] : 0.f;
    F[PW6 + i] = (d < 15) ? a.W6[r*15 + d] : 0.f;
  }
  for (int i = gt; i < 150*32; i += nt) {
    int r = i >> 5, d = i & 31; float v = 0.f;
    if (d < 15) v = a.W7[r*30 + d];
    else if (d >= 16 && d < 31) v = a.W7[r*30 + 15 + d - 16];
    F[PW7 + i] = v;
  }
  for (long long i = gt; i < 18000LL*452; i += nt) {
    long long r = i/452; int d = (int)(i - r*452);
    F[W2AP + i] = (d < 450) ? a.W2a[r*450 + d] : 0.f;
  }
}

__global__ __launch_bounds__(NTH, 4) void knet_main(KArgs a) {
  __shared__ float smem[L_TOTAL];
  const int tid  = threadIdx.x;
  const int widx = tid >> 6;
  const int l    = tid & 63;
  const int bx   = (int)blockIdx.x;
  const int k0   = l*4;
  float* F  = a.fb;
  int*   ib = a.ib;
  int ep = 0;

  // One-time: preload this WG's constant W2b tile [45][400] into LDS.
  if (bx < 225) {
    const int jt = bx / 45, kc = bx - jt*45;
    const int j0 = jt*45, col0 = kc*400;
    for (int idx = tid; idx < 4500; idx += NTH) {
      int jj = idx / 100, cc = idx - jj*100;
      *(float4*)(smem + LW2B + jj*400 + cc*4) =
          ldg4(a.W2b + (size_t)(j0+jj)*18000 + col0 + cc*4);
    }
  }
  __syncthreads();

  for (int t = 0; t < TT; ++t) {
    const int p = t & 1, q = p ^ 1;
    float* hQi = F + F_HQ + p*3648;  float* hQo = F + F_HQ + q*3648;
    float* hSi = F + F_HS + p*3648;  float* hSo = F + F_HS + q*3648;

    // ==== A: out5(LDS) ; hQ GRU ; hSig = out4(prev osig,out3) ==============
    if (bx < 225) {
      if (tid < 64) {
        v4f v = {0.f,0.f,0.f,0.f};
        cld4r(v, F + F_FWD + tid*4);
        CW1(v);
        *(float4*)(smem + L_SCR + tid*4) = v2f(v);
      }
      __syncthreads();
      for (int i = tid; i < 1200; i += NTH) {
        int bb = i/75, j5 = i - bb*75;
        const float4* w  = (const float4*)(F + PW5 + j5*16);
        const float4* xv = (const float4*)(smem + L_SCR + bb*16);
        float acc = a.b5[j5];
        acc = dp4(acc, w[0], xv[0]); acc = dp4(acc, w[1], xv[1]);
        acc = dp4(acc, w[2], xv[2]); acc = dp4(acc, w[3], xv[3]);
        smem[L_OUT5 + bb*76 + j5] = fmaxf(acc, 0.f);
      }
      __syncthreads();
      const int j = bx, bw = widx;
      v4f tq0 = {0.f,0.f,0.f,0.f}, tq1 = {0.f,0.f,0.f,0.f};
      v4f tw0 = {0.f,0.f,0.f,0.f}, tw1 = {0.f,0.f,0.f,0.f};
      if (k0 >= 76) cld4r(tq0, hQi + bw*228 + k0 - 76);
      if (l < 12)   cld4r(tq1, hQi + bw*228 + 180 + k0);
      cld4r(tw0, (l < 57) ? (F + F_OSIG + bw*228 + k0)
                          : (F + F_OUT3 + bw*228 + k0 - 228));
      if (l < 50)   cld4r(tw1, F + F_OUT3 + bw*228 + 28 + k0);
      CW4(tq0, tq1, tw0, tw1);
      float4 xq0 = (k0 < 76) ? *(const float4*)(smem + L_OUT5 + bw*76 + k0)
                             : v2f(tq0);
      float4 xq1 = v2f(tq1);
      float4 xw0 = v2f(tw0);
      float4 xw1 = v2f(tw1);
      const float* qr = F + PQ + (size_t)j*304;
      const float* qz = qr + 225*304;
      const float* qn = qr + 450*304;
      const float* w4r = F + PW4 + (size_t)j*456;
      float4 wr0 = ldg4(qr + k0), wz0 = ldg4(qz + k0), wn0 = ldg4(qn + k0);
      float4 w40 = ldg4(w4r + k0);
      float ar=0.f, az=0.f, ani=0.f, anh=0.f, a4=0.f;
      ar = dp4(ar, wr0, xq0); az = dp4(az, wz0, xq0);
      { float tt = dp4(0.f, wn0, xq0); if (k0 < 76) ani += tt; else anh += tt; }
      a4 = dp4(a4, w40, xw0);
      if (l < 12) {
        float4 wr1 = ldg4(qr + 256 + k0), wz1 = ldg4(qz + 256 + k0), wn1 = ldg4(qn + 256 + k0);
        ar = dp4(ar, wr1, xq1); az = dp4(az, wz1, xq1); anh = dp4(anh, wn1, xq1);
      }
      if (l < 50) a4 = dp4(a4, ldg4(w4r + 256 + k0), xw1);
      ar = red64(ar); az = red64(az); ani = red64(ani); anh = red64(anh); a4 = red64(a4);
      if (l == 0) {
        float r = sigf(ar + a.bihQ[j] + a.bhhQ[j]);
        float z = sigf(az + a.bihQ[225+j] + a.bhhQ[225+j]);
        float n = tanhf(ani + a.bihQ[450+j] + r*(anh + a.bhhQ[450+j]));
        ast(&hQo[bw*228 + j], (1.f - z)*n + z*ald(&hQi[bw*228 + j]));
        if (t > 0) ast(&F[F_HSIG + bw*228 + j], fmaxf(a4 + a.b4[j], 0.f));
      }
    } else if (bx == 225) {
      // zero out2 for this step's F-stage atomic accumulation
      for (int i = tid; i < 912; i += NTH)
        ast4(&F[F_OUT2 + i*4], make_float4(0.f, 0.f, 0.f, 0.f));
    }
    gbar(ib, ep); ++ep;

    // ==== B: out6(LDS) ; osig GRU (x=[hQ|out6], h=hSig) ====================
    if (bx < 225) {
      // FWD still in L_SCR from stage A
      for (int i = tid; i < 1200; i += NTH) {
        int bb = i/75, j6 = i - bb*75;
        const float4* w  = (const float4*)(F + PW6 + j6*16);
        const float4* xv = (const float4*)(smem + L_SCR + bb*16);
        float acc = a.b6[j6];
        acc = dp4(acc, w[0], xv[0]); acc = dp4(acc, w[1], xv[1]);
        acc = dp4(acc, w[2], xv[2]); acc = dp4(acc, w[3], xv[3]);
        smem[L_OUT6 + bb*76 + j6] = fmaxf(acc, 0.f);
      }
      __syncthreads();
      const int j = bx, bw = widx;
      v4f t0 = {0.f,0.f,0.f,0.f}, t1 = {0.f,0.f,0.f,0.f}, t2 = {0.f,0.f,0.f,0.f};
      if (l < 57)  cld4r(t0, hQo + bw*228 + k0);
      if (l >= 12) cld4r(t1, F + F_HSIG + bw*228 + k0 - 48);
      if (l < 5)   cld4r(t2, F + F_HSIG + bw*228 + 208 + k0);
      CW3(t0, t1, t2);
      float4 x0 = (l < 57) ? v2f(t0)
                           : *(const float4*)(smem + L_OUT6 + bw*76 + k0 - 228);
      float4 x1 = (l < 12) ? *(const float4*)(smem + L_OUT6 + bw*76 + 28 + k0)
                           : v2f(t1);
      float4 x2 = v2f(t2);
      const float* gr = F + PSIG + (size_t)j*544;
      const float* gz = gr + 225*544;
      const float* gn = gr + 450*544;
      float4 wr0 = ldg4(gr + k0),     wz0 = ldg4(gz + k0),     wn0 = ldg4(gn + k0);
      float4 wr1 = ldg4(gr + 256+k0), wz1 = ldg4(gz + 256+k0), wn1 = ldg4(gn + 256+k0);
      float ar=0.f, az=0.f, ani=0.f, anh=0.f;
      ar = dp4(ar, wr0, x0); az = dp4(az, wz0, x0); ani = dp4(ani, wn0, x0);
      ar = dp4(ar, wr1, x1); az = dp4(az, wz1, x1);
      { float tt = dp4(0.f, wn1, x1); if (l < 12) ani += tt; else anh += tt; }
      if (l < 5) {
        float4 wr2 = ldg4(gr + 512+k0), wz2 = ldg4(gz + 512+k0), wn2 = ldg4(gn + 512+k0);
        ar = dp4(ar, wr2, x2); az = dp4(az, wz2, x2); anh = dp4(anh, wn2, x2);
      }
      ar = red64(ar); az = red64(az); ani = red64(ani); anh = red64(anh);
      if (l == 0) {
        float r = sigf(ar + a.bihSig[j] + a.bhhSig[j]);
        float z = sigf(az + a.bihSig[225+j] + a.bhhSig[225+j]);
        float n = tanhf(ani + a.bihSig[450+j] + r*(anh + a.bhhSig[450+j]));
        float val = (1.f - z)*n + z*ald(&F[F_HSIG + bw*228 + j]);
        ast(&F[F_OSIG + bw*228 + j], val);
        ast(&F[F_XV + bw*452 + j], val);
      }
    }
    gbar(ib, ep); ++ep;

    // ==== C: out1 = relu(W1 @ osig + b1) ===================================
    if (bx < 225) {
      const int j = bx, bw = widx;
      float acc = 0.f;
      v4f t0 = {0.f,0.f,0.f,0.f};
      if (l < 57) cld4r(t0, F + F_OSIG + bw*228 + k0);
      CW1(t0);
      if (l < 57) {
        float4 w0 = ldg4(F + PW1 + (size_t)j*228 + k0);
        acc = dp4(0.f, w0, v2f(t0));
      }
      acc = red64(acc);
      if (l == 0) ast(&F[F_OUT1 + bw*228 + j], fmaxf(acc + a.b1[j], 0.f));
    }
    gbar(ib, ep); ++ep;

    // ==== D: out7(LDS) ; hS GRU (x=[out1|out7], h=hS) ======================
    if (bx < 225) {
      if (tid < 128) {
        v4f v = {0.f,0.f,0.f,0.f};
        cld4r(v, (tid < 64) ? (F + F_OBSD + tid*4) : (F + F_DY + (tid-64)*4));
        CW1(v);
        *(float4*)(smem + L_SCR + tid*4) = v2f(v);
      }
      __syncthreads();
      for (int i = tid; i < 2400; i += NTH) {
        int bb = i/150, j7 = i - bb*150;
        const float4* w  = (const float4*)(F + PW7 + j7*32);
        const float4* vo = (const float4*)(smem + L_SCR + bb*16);
        const float4* vd = (const float4*)(smem + L_SCR + 256 + bb*16);
        float acc = a.b7[j7];
        acc = dp4(acc, w[0], vo[0]); acc = dp4(acc, w[1], vo[1]);
        acc = dp4(acc, w[2], vo[2]); acc = dp4(acc, w[3], vo[3]);
        acc = dp4(acc, w[4], vd[0]); acc = dp4(acc, w[5], vd[1]);
        acc = dp4(acc, w[6], vd[2]); acc = dp4(acc, w[7], vd[3]);
        smem[L_OUT7 + bb*152 + j7] = fmaxf(acc, 0.f);
      }
      __syncthreads();
      const int j = bx, bw = widx;
      v4f t0 = {0.f,0.f,0.f,0.f}, t1 = {0.f,0.f,0.f,0.f}, t2 = {0.f,0.f,0.f,0.f};
      if (l < 57)  cld4r(t0, F + F_OUT1 + bw*228 + k0);
      if (l >= 31) cld4r(t1, hSi + bw*228 + k0 - 124);
      if (l < 24)  cld4r(t2, hSi + bw*228 + 132 + k0);
      CW3(t0, t1, t2);
      float4 x0 = (l < 57) ? v2f(t0)
                           : *(const float4*)(smem + L_OUT7 + bw*152 + k0 - 228);
      float4 x1 = (l < 31) ? *(const float4*)(smem + L_OUT7 + bw*152 + 28 + k0)
                           : v2f(t1);
      float4 x2 = v2f(t2);
      const float* gr = F + PS + (size_t)j*608;
      const float* gz = gr + 225*608;
      const float* gn = gr + 450*608;
      float4 wr0 = ldg4(gr + k0),     wz0 = ldg4(gz + k0),     wn0 = ldg4(gn + k0);
      float4 wr1 = ldg4(gr + 256+k0), wz1 = ldg4(gz + 256+k0), wn1 = ldg4(gn + 256+k0);
      float ar=0.f, az=0.f, ani=0.f, anh=0.f;
      ar = dp4(ar, wr0, x0); az = dp4(az, wz0, x0); ani = dp4(ani, wn0, x0);
      ar = dp4(ar, wr1, x1); az = dp4(az, wz1, x1);
      { float tt = dp4(0.f, wn1, x1); if (l < 31) ani += tt; else anh += tt; }
      if (l < 24) {
        float4 wr2 = ldg4(gr + 512+k0), wz2 = ldg4(gz + 512+k0), wn2 = ldg4(gn + 512+k0);
        ar = dp4(ar, wr2, x2); az = dp4(az, wz2, x2); anh = dp4(anh, wn2, x2);
      }
      ar = red64(ar); az = red64(az); ani = red64(ani); anh = red64(anh);
      if (l == 0) {
        float r = sigf(ar + a.bihS[j] + a.bhhS[j]);
        float z = sigf(az + a.bihS[225+j] + a.bhhS[225+j]);
        float n = tanhf(ani + a.bihS[450+j] + r*(anh + a.bhhS[450+j]));
        float val = (1.f - z)*n + z*ald(&hSi[bw*228 + j]);
        ast(&hSo[bw*228 + j], val);
        ast(&F[F_XV + bw*452 + 225 + j], val);
      }
    }
    gbar(ib, ep); ++ep;

    // ==== E: hid2 = relu(W2aP @ xv + b2a) — 2 rows x 16 b per wave =========
    {
      {
        const int i0 = tid, i1 = tid + NTH;
        v4f v0 = {0.f,0.f,0.f,0.f}, v1 = {0.f,0.f,0.f,0.f};
        cld4r(v0, F + F_XV + i0*4);
        if (i1 < 1808) cld4r(v1, F + F_XV + i1*4);
        CW2(v0, v1);
        *(float4*)(smem + L_XV + i0*4) = v2f(v0);
        if (i1 < 1808) *(float4*)(smem + L_XV + i1*4) = v2f(v1);
      }
      __syncthreads();
      if (bx < 250) {
        const int r0 = bx*72;
        for (int ps = 0; ps < 3; ++ps) {
          const int pi = ps*16 + widx;
          if (pi >= 36) break;
          const int rA = r0 + 2*pi;
          const float* wAp = F + W2AP + (size_t)rA*452;
          const float* wBp = wAp + 452;
          float aA[16], aB[16];
          #pragma unroll
          for (int i = 0; i < 16; ++i) { aA[i] = 0.f; aB[i] = 0.f; }
          {
            float4 wA = ldg4(wAp + k0), wB = ldg4(wBp + k0);
            #pragma unroll
            for (int bb = 0; bb < 16; ++bb) {
              float4 xv = *(const float4*)(smem + L_XV + bb*452 + k0);
              aA[bb] = dp4(aA[bb], wA, xv);
              aB[bb] = dp4(aB[bb], wB, xv);
            }
          }
          if (l < 49) {
            float4 wA = ldg4(wAp + 256 + k0), wB = ldg4(wBp + 256 + k0);
            #pragma unroll
            for (int bb = 0; bb < 16; ++bb) {
              float4 xv = *(const float4*)(smem + L_XV + bb*452 + 256 + k0);
              aA[bb] = dp4(aA[bb], wA, xv);
              aB[bb] = dp4(aB[bb], wB, xv);
            }
          }
          #pragma unroll
          for (int i = 0; i < 16; ++i) { aA[i] = red64(aA[i]); aB[i] = red64(aB[i]); }
          if (l == 0) {
            float bA = a.b2a[rA], bB = a.b2a[rA + 1];
            #pragma unroll
            for (int i = 0; i < 16; ++i)
              ast2(&F[F_HID2 + i*18000 + rA],
                   fmaxf(aA[i] + bA, 0.f), fmaxf(aB[i] + bB, 0.f));
          }
        }
      }
    }
    gbar(ib, ep); ++ep;

    // ==== F: out2 += W2b(LDS) @ hid2-chunk — 225 WGs: jt=bx/45, kc=bx%45 ===
    // W2b tile persistent in LDS; no staging, no internal barriers.
    if (bx < 225) {
      const int jt = bx / 45, kc = bx - jt*45;
      const int j0 = jt*45, col0 = kc*400;
      const int b = widx;
      const float* hb = F + F_HID2 + (size_t)b*18000 + col0;
      v4f h0v = {0.f,0.f,0.f,0.f}, h1v = {0.f,0.f,0.f,0.f};
      cld4r(h0v, hb + 4*l);
      if (l < 36) cld4r(h1v, hb + 256 + 4*l);
      CW2(h0v, h1v);
      float4 h0 = v2f(h0v), h1 = v2f(h1v);
      #pragma unroll 5
      for (int jj = 0; jj < 45; ++jj) {
        const float* wrow = smem + LW2B + jj*400;
        float acc = dp4(0.f, *(const float4*)(wrow + 4*l), h0);
        if (l < 36) acc = dp4(acc, *(const float4*)(wrow + 256 + 4*l), h1);
        acc = red64(acc);
        if (l == 0) aadd(&F[F_OUT2 + b*228 + j0 + jj], acc);
      }
    }
    gbar(ib, ep); ++ep;

    // ==== G: out2(LDS) ; out3 = relu(W3@[hS|out2]+b3) ; x update ===========
    if (bx < 225) {
      if (tid < 912) {
        v4f pq = {0.f,0.f,0.f,0.f};
        cld4r(pq, F + F_OUT2 + tid*4);
        CW1(pq);
        int bb = tid / 57, c = tid - bb*57;
        int j2 = c*4;
        float4 v;
        v.x = (j2+0 < 225) ? pq.x + a.b2b[j2+0] : 0.f;
        v.y = (j2+1 < 225) ? pq.y + a.b2b[j2+1] : 0.f;
        v.z = (j2+2 < 225) ? pq.z + a.b2b[j2+2] : 0.f;
        v.w = (j2+3 < 225) ? pq.w + a.b2b[j2+3] : 0.f;
        *(float4*)(smem + L_OUT2 + tid*4) = v;
      }
      __syncthreads();
      const int j = bx, bw = widx;
      v4f t0 = {0.f,0.f,0.f,0.f};
      if (l < 57) cld4r(t0, hSo + bw*228 + k0);
      CW1(t0);
      float4 x0 = (l < 57) ? v2f(t0)
                           : *(const float4*)(smem + L_OUT2 + bw*228 + k0 - 228);
      float4 x1; if (l < 50) x1 = *(const float4*)(smem + L_OUT2 + bw*228 + 28 + k0);
      const float* w3r = F + PW3 + (size_t)j*456;
      float acc = dp4(0.f, ldg4(w3r + k0), x0);
      if (l < 50) acc = dp4(acc, ldg4(w3r + 256 + k0), x1);
      acc = red64(acc);
      if (l == 0) ast(&F[F_OUT3 + bw*228 + j], fmaxf(acc + a.b3[j], 0.f));
    } else if (bx == 225) {
      for (int i = tid; i < 240; i += NTH) {
        int bb = i/15, jj = i - bb*15;
        float o2 = ald(&F[F_OUT2 + bb*228 + jj]) + a.b2b[jj];
        float xold = ald(&F[F_XP + i]), dy = ald(&F[F_DY + bb*16 + jj]);
        float xnew = fmaf(o2, dy, xold);
        a.out[t*240 + i] = xnew;
        ast(&F[F_XP + i], xnew);
        if (t + 1 < TT) {
          float y1 = a.y[(t+1)*480 + bb*30 + jj];
          float y0 = a.y[t*480     + bb*30 + jj];
          ast(&F[F_DY   + bb*16 + jj], y1 - xnew);
          ast(&F[F_OBSD + bb*16 + jj], y1 - y0);
          ast(&F[F_FWD  + bb*16 + jj], xnew - xold);
        }
      }
    }
    gbar(ib, ep); ++ep;
  }
}

extern "C" void kernel_launch(void* const* d_in, const int* in_sizes, int n_in,
                              void* d_out, int out_size, void* d_ws, size_t ws_size,
                              hipStream_t stream) {
  (void)in_sizes; (void)n_in; (void)out_size; (void)ws_size;
  KArgs a;
  int k = 0;
  a.y      = (const float*)d_in[k++];
  a.x0     = (const float*)d_in[k++];
  a.hQ0    = (const float*)d_in[k++];
  a.hSig0  = (const float*)d_in[k++];
  a.hS0    = (const float*)d_in[k++];
  a.WihQ   = (const float*)d_in[k++];
  a.WhhQ   = (const float*)d_in[k++];
  a.bihQ   = (const float*)d_in[k++];
  a.bhhQ   = (const float*)d_in[k++];
  a.WihSig = (const float*)d_in[k++];
  a.WhhSig = (const float*)d_in[k++];
  a.bihSig = (const float*)d_in[k++];
  a.bhhSig = (const float*)d_in[k++];
  a.WihS   = (const float*)d_in[k++];
  a.WhhS   = (const float*)d_in[k++];
  a.bihS   = (const float*)d_in[k++];
  a.bhhS   = (const float*)d_in[k++];
  a.W1  = (const float*)d_in[k++];  a.b1  = (const float*)d_in[k++];
  a.W2a = (const float*)d_in[k++];  a.b2a = (const float*)d_in[k++];
  a.W2b = (const float*)d_in[k++];  a.b2b = (const float*)d_in[k++];
  a.W3  = (const float*)d_in[k++];  a.b3  = (const float*)d_in[k++];
  a.W4  = (const float*)d_in[k++];  a.b4  = (const float*)d_in[k++];
  a.W5  = (const float*)d_in[k++];  a.b5  = (const float*)d_in[k++];
  a.W6  = (const float*)d_in[k++];  a.b6  = (const float*)d_in[k++];
  a.W7  = (const float*)d_in[k++];  a.b7  = (const float*)d_in[k++];
  a.out = (float*)d_out;
  a.ib  = (int*)d_ws;
  a.fb  = (float*)((char*)d_ws + (size_t)INT_TOTAL*sizeof(int));

  hipLaunchKernelGGL(knet_init, dim3(2048), dim3(256), 0, stream, a);
  hipLaunchKernelGGL(knet_main, dim3(NWG), dim3(NTH), 0, stream, a);
}